// Round 4
// baseline (771.415 us; speedup 1.0000x reference)
//
#include <hip/hip_runtime.h>
#include <hip/hip_bf16.h>

#define DIM 2048
#define SEQ 2048
#define NH 32
#define HD 64
#define NKV 8
#define QKV_LD 3072

typedef __attribute__((ext_vector_type(8))) short bf16x8;
typedef __attribute__((ext_vector_type(4))) float f32x4;
typedef unsigned short ushort_t;

__device__ inline unsigned short f2bf(float f) {
    union { float f; unsigned int u; } v; v.f = f;
    unsigned int r = v.u + 0x7fffu + ((v.u >> 16) & 1u);
    return (unsigned short)(r >> 16);
}
__device__ inline float bf2f(ushort_t u) {
    union { unsigned int u; float f; } v; v.u = ((unsigned int)u) << 16; return v.f;
}

// ---------------------------------------------------------------------------
// Input-storage detector (see round-2 notes). Evidence so far says inputs are
// true fp32 (rounds 2&3 agreed + bit-identical outputs); kept for robustness.
// flags[0]=1 iff bf16 storage. flags[1]=1 const.
// ---------------------------------------------------------------------------
__global__ void detect_kernel(const ushort_t* __restrict__ x, int* __restrict__ flags)
{
    int lane = threadIdx.x;                      // 64 threads
    ushort_t u = x[2 * lane];
    float af = fabsf(bf2f(u));
    bool sane = (u != 0) && af > 1e-6f && af < 1e6f;
    unsigned long long bs = __ballot(sane);
    if (lane == 0) {
        flags[0] = (__popcll(bs) >= 48) ? 1 : 0;
        flags[1] = 1;
    }
}

// Load 8 consecutive elements as bf16, converting from fp32 if needed.
__device__ inline void load8bf(const void* base, size_t off, int isbf, ushort_t* out8)
{
    if (isbf) {
        *(uint4*)out8 = *(const uint4*)((const ushort_t*)base + off);
    } else {
        const float* p = (const float*)base + off;
        float4 f0 = *(const float4*)p;
        float4 f1 = *(const float4*)(p + 4);
        out8[0] = f2bf(f0.x); out8[1] = f2bf(f0.y);
        out8[2] = f2bf(f0.z); out8[3] = f2bf(f0.w);
        out8[4] = f2bf(f1.x); out8[5] = f2bf(f1.y);
        out8[6] = f2bf(f1.z); out8[7] = f2bf(f1.w);
    }
}

// ---------------------------------------------------------------------------
// GEMM: C[M,N] = A[M,K] * B[K,N], A/B row-major, input dtype per flag.
// OUT_F32=0: write bf16 (ushort). OUT_F32=1: write fp32 (d_out is float*).
// 64x64 tile per 256-thread block, K-step 32, mfma_f32_16x16x32_bf16.
// Grid: (N/64, M/64).
// ---------------------------------------------------------------------------
template<int OUT_F32>
__global__ __launch_bounds__(256) void gemm_kernel(
    const void* __restrict__ A, const void* __restrict__ B,
    void* __restrict__ Cout, int K, int lda, int ldb, int ldo,
    const int* __restrict__ aflag, const int* __restrict__ bflag)
{
    __shared__ ushort_t sA[64][40];   // A[m][k], padded stride 40
    __shared__ ushort_t sB[64][40];   // B^T: sB[n][k], padded stride 40

    const int isa = *aflag;
    const int isb = *bflag;

    const int tn = blockIdx.x * 64;
    const int tm = blockIdx.y * 64;
    const int t = threadIdx.x;
    const int wave = t >> 6;
    const int lane = t & 63;
    const int m16 = lane & 15;
    const int quad = lane >> 4;

    f32x4 acc[4] = {};

    const int ar = t >> 2, ac = (t & 3) * 8;   // A staging: 64 rows x 32 cols
    const int bk = t >> 3, bn = (t & 7) * 8;   // B staging: 32 rows x 64 cols

    for (int k0 = 0; k0 < K; k0 += 32) {
        ushort_t av[8], bv[8];
        load8bf(A, (size_t)(tm + ar) * lda + k0 + ac, isa, av);
        load8bf(B, (size_t)(k0 + bk) * ldb + tn + bn, isb, bv);
        __syncthreads();
        *(uint4*)&sA[ar][ac] = *(uint4*)av;
        #pragma unroll
        for (int j = 0; j < 8; j++) sB[bn + j][bk] = bv[j];   // transpose into LDS
        __syncthreads();

        bf16x8 afrag = *(const bf16x8*)&sA[wave * 16 + m16][quad * 8];
        #pragma unroll
        for (int nt = 0; nt < 4; nt++) {
            bf16x8 bfrag = *(const bf16x8*)&sB[nt * 16 + m16][quad * 8];
            acc[nt] = __builtin_amdgcn_mfma_f32_16x16x32_bf16(afrag, bfrag, acc[nt], 0, 0, 0);
        }
    }

    const int orow = tm + wave * 16 + quad * 4;
    if (OUT_F32) {
        float* O = (float*)Cout;
        #pragma unroll
        for (int nt = 0; nt < 4; nt++)
            #pragma unroll
            for (int r = 0; r < 4; r++)
                O[(size_t)(orow + r) * ldo + tn + nt * 16 + m16] = acc[nt][r];
    } else {
        ushort_t* O = (ushort_t*)Cout;
        #pragma unroll
        for (int nt = 0; nt < 4; nt++)
            #pragma unroll
            for (int r = 0; r < 4; r++)
                O[(size_t)(orow + r) * ldo + tn + nt * 16 + m16] = f2bf(acc[nt][r]);
    }
}

// ---------------------------------------------------------------------------
// In-place RoPE on one 64-element head slice per thread.
// out[i]    = v[i]*cos(s*f_i) - v[2i+1]*sin(s*f_i)     (i in [0,32))
// out[i+32] = v[i+32]*cos(s*f_i) + v[2i]*sin(s*f_i)
// Thread owns the whole slice: read-all-then-write-all, no races.
// ---------------------------------------------------------------------------
template<int COLS0, int HB>
__global__ void rope_kernel(ushort_t* qkv)
{
    int gid = blockIdx.x * 256 + threadIdx.x;
    int h = gid & (HB - 1);
    int s = gid / HB;
    ushort_t* row = qkv + (size_t)s * QKV_LD + COLS0 + h * 64;

    uint4 w[8];
    #pragma unroll
    for (int t = 0; t < 8; t++) w[t] = *(const uint4*)(row + t * 8);
    ushort_t* u = (ushort_t*)w;

    float v[64], o[64];
    #pragma unroll
    for (int j = 0; j < 64; j++) v[j] = bf2f(u[j]);

    #pragma unroll
    for (int i = 0; i < 32; i++) {
        float freq = __expf(-(float)i * 0.28782313662425572f);  // ln(10000)/32
        float ang = (float)s * freq;
        float sv = sinf(ang), cv = cosf(ang);
        o[i]      = v[i]      * cv - v[2 * i + 1] * sv;
        o[i + 32] = v[i + 32] * cv + v[2 * i]     * sv;
    }

    #pragma unroll
    for (int j = 0; j < 64; j++) u[j] = f2bf(o[j]);
    #pragma unroll
    for (int t = 0; t < 8; t++) *(uint4*)(row + t * 8) = w[t];
}

// V transpose: Vt[kvh][d][s] = qkv[s][2560 + kvh*64 + d]
__global__ void vtrans_kernel(const ushort_t* __restrict__ qkv, ushort_t* __restrict__ Vt)
{
    int gid = blockIdx.x * 256 + threadIdx.x;   // SEQ*NKV*64 threads
    int d = gid & 63;
    int kh = (gid >> 6) & 7;
    int s = gid >> 9;
    Vt[((size_t)kh * 64 + d) * SEQ + s] = qkv[(size_t)s * QKV_LD + 2560 + kh * 64 + d];
}

// ---------------------------------------------------------------------------
// Flash attention. Q from qkv cols [h*64, ...), K from cols [2048+kvh*64, ...),
// output written back into the q-region cells the wave itself read.
// One wave per (head, 16-query tile); block = 4 waves, same head, uniform trips.
// ---------------------------------------------------------------------------
__global__ __launch_bounds__(256) void attn_kernel(
    ushort_t* qkv, const ushort_t* __restrict__ Vt)
{
    __shared__ float sP[4][16][36];   // per-wave P round-trip (C-layout -> A-layout)

    const int wave = threadIdx.x >> 6;
    const int lane = threadIdx.x & 63;
    const int m16 = lane & 15;
    const int quad = lane >> 4;

    const int h = blockIdx.x >> 5;          // 32 q-groups per head
    const int qg = blockIdx.x & 31;
    const int qt = qg * 4 + wave;
    const int kvh = h >> 2;                 // h / NREP
    const int q0 = qt * 16;

    const ushort_t* Qb = qkv + h * 64;                 // [s][.] stride QKV_LD
    const ushort_t* Kb = qkv + 2048 + kvh * 64;        // [s][.] stride QKV_LD
    const ushort_t* Vh = Vt + (size_t)kvh * 64 * SEQ;  // [d][s]

    bf16x8 qf0 = *(const bf16x8*)(Qb + (size_t)(q0 + m16) * QKV_LD + quad * 8);
    bf16x8 qf1 = *(const bf16x8*)(Qb + (size_t)(q0 + m16) * QKV_LD + 32 + quad * 8);

    f32x4 oacc[4] = {};
    float m_run[4], l_run[4];
    #pragma unroll
    for (int r = 0; r < 4; r++) { m_run[r] = -1e30f; l_run[r] = 0.f; }

    const int last_q = (qg * 4 + 3) * 16 + 15;    // block-uniform
    const int nkt = last_q / 32 + 1;

    for (int kt = 0; kt < nkt; kt++) {
        const int kbase = kt * 32;

        // ---- QK^T: S-tile 16(q) x 32(keys) ----
        f32x4 sc[2] = {};
        #pragma unroll
        for (int knt = 0; knt < 2; knt++) {
            const ushort_t* kp = Kb + (size_t)(kbase + knt * 16 + m16) * QKV_LD + quad * 8;
            bf16x8 kf0 = *(const bf16x8*)kp;
            bf16x8 kf1 = *(const bf16x8*)(kp + 32);
            sc[knt] = __builtin_amdgcn_mfma_f32_16x16x32_bf16(qf0, kf0, sc[knt], 0, 0, 0);
            sc[knt] = __builtin_amdgcn_mfma_f32_16x16x32_bf16(qf1, kf1, sc[knt], 0, 0, 0);
        }

        // ---- scale + causal mask + online softmax (C-layout rows quad*4+r) ----
        float alpha[4];
        #pragma unroll
        for (int r = 0; r < 4; r++) {
            const int qi = q0 + quad * 4 + r;
            float s0 = sc[0][r] * 0.125f;
            float s1 = sc[1][r] * 0.125f;
            if (kbase + m16 > qi)      s0 = -1e30f;
            if (kbase + 16 + m16 > qi) s1 = -1e30f;
            float rmax = fmaxf(s0, s1);
            #pragma unroll
            for (int off = 1; off < 16; off <<= 1)
                rmax = fmaxf(rmax, __shfl_xor(rmax, off, 64));
            float mnew = fmaxf(m_run[r], rmax);
            alpha[r] = __expf(m_run[r] - mnew);
            m_run[r] = mnew;
            float p0 = __expf(s0 - mnew);
            float p1 = __expf(s1 - mnew);
            sc[0][r] = p0; sc[1][r] = p1;
            float ps = p0 + p1;
            #pragma unroll
            for (int off = 1; off < 16; off <<= 1)
                ps += __shfl_xor(ps, off, 64);
            l_run[r] = l_run[r] * alpha[r] + ps;
        }

        // ---- P: C-layout -> A-layout via LDS ----
        #pragma unroll
        for (int knt = 0; knt < 2; knt++)
            #pragma unroll
            for (int r = 0; r < 4; r++)
                sP[wave][quad * 4 + r][knt * 16 + m16] = sc[knt][r];
        __syncthreads();
        bf16x8 pfrag;
        #pragma unroll
        for (int j = 0; j < 8; j++)
            pfrag[j] = (short)f2bf(sP[wave][m16][quad * 8 + j]);
        __syncthreads();

        // ---- O = O*alpha + P@V (K-dim = 32 keys) ----
        #pragma unroll
        for (int nt = 0; nt < 4; nt++) {
            #pragma unroll
            for (int r = 0; r < 4; r++) oacc[nt][r] *= alpha[r];
            bf16x8 vf = *(const bf16x8*)(Vh + (size_t)(nt * 16 + m16) * SEQ + kbase + quad * 8);
            oacc[nt] = __builtin_amdgcn_mfma_f32_16x16x32_bf16(pfrag, vf, oacc[nt], 0, 0, 0);
        }
    }

    // ---- epilogue: O / l -> qkv q-region [qi][h*64+d] ----
    #pragma unroll
    for (int nt = 0; nt < 4; nt++) {
        #pragma unroll
        for (int r = 0; r < 4; r++) {
            const int qi = q0 + quad * 4 + r;
            const int d = nt * 16 + m16;
            qkv[(size_t)qi * QKV_LD + h * 64 + d] = f2bf(oacc[nt][r] / l_run[r]);
        }
    }
}

// ---------------------------------------------------------------------------
extern "C" void kernel_launch(void* const* d_in, const int* in_sizes, int n_in,
                              void* d_out, int out_size, void* d_ws, size_t ws_size,
                              hipStream_t stream)
{
    const void* x  = d_in[0];
    // d_in[1] = mask (int32) — causal, handled analytically
    const void* wq = d_in[2];
    const void* wk = d_in[3];
    const void* wv = d_in[4];
    const void* wo = d_in[5];

    int* flags = (int*)d_ws;                  // 64 B header
    char* base = (char*)d_ws + 64;
    ushort_t* qkv = (ushort_t*)base;                                   // 12.58 MB
    ushort_t* Vt  = (ushort_t*)(base + (size_t)SEQ * QKV_LD * 2);      // 2.10 MB

    dim3 blk(256);

    detect_kernel<<<1, 64, 0, stream>>>((const ushort_t*)x, flags);

    // QKV projections -> qkv bf16 [s][3072]
    gemm_kernel<0><<<dim3(DIM / 64, SEQ / 64), blk, 0, stream>>>(x, wq, qkv,        DIM, DIM, DIM, QKV_LD, flags, flags);
    gemm_kernel<0><<<dim3(512 / 64, SEQ / 64), blk, 0, stream>>>(x, wk, qkv + 2048, DIM, DIM, 512, QKV_LD, flags, flags);
    gemm_kernel<0><<<dim3(512 / 64, SEQ / 64), blk, 0, stream>>>(x, wv, qkv + 2560, DIM, DIM, 512, QKV_LD, flags, flags);

    // RoPE (in-place) + V transpose
    rope_kernel<0,    NH> <<<(SEQ * NH)  / 256, blk, 0, stream>>>(qkv);
    rope_kernel<2048, NKV><<<(SEQ * NKV) / 256, blk, 0, stream>>>(qkv);
    vtrans_kernel<<<(SEQ * NKV * 64) / 256, blk, 0, stream>>>(qkv, Vt);

    // Flash attention (output overwrites qkv q-region)
    attn_kernel<<<NH * 32, blk, 0, stream>>>(qkv, Vt);

    // Output projection -> d_out fp32 (reference output dtype is float32)
    gemm_kernel<1><<<dim3(DIM / 64, SEQ / 64), blk, 0, stream>>>(qkv, wo, d_out, DIM, QKV_LD, DIM, DIM, flags + 1, flags);
}

// Round 5
// 429.110 us; speedup vs baseline: 1.7977x; 1.7977x over previous
//
#include <hip/hip_runtime.h>
#include <hip/hip_bf16.h>

#define DIM 2048
#define SEQ 2048
#define NH 32
#define HD 64
#define NKV 8
#define QKV_LD 3072

typedef __attribute__((ext_vector_type(8))) short bf16x8;
typedef __attribute__((ext_vector_type(4))) float f32x4;
typedef unsigned short ushort_t;

__device__ inline unsigned short f2bf(float f) {
    union { float f; unsigned int u; } v; v.f = f;
    unsigned int r = v.u + 0x7fffu + ((v.u >> 16) & 1u);
    return (unsigned short)(r >> 16);
}
__device__ inline float bf2f(ushort_t u) {
    union { unsigned int u; float f; } v; v.u = ((unsigned int)u) << 16; return v.f;
}

// async global->LDS, 16B per lane. LDS dest is wave-uniform base + lane*16.
__device__ inline void async_cp16(const void* g, void* l) {
    __builtin_amdgcn_global_load_lds(
        (const __attribute__((address_space(1))) unsigned int*)g,
        (__attribute__((address_space(3))) unsigned int*)l, 16, 0, 0);
}
__device__ inline void lgkm_fence() {
    __asm__ volatile("s_waitcnt lgkmcnt(0)" ::: "memory");
}

// ---------------------------------------------------------------------------
// x fp32 -> bf16 (4 elems/thread)
// ---------------------------------------------------------------------------
__global__ __launch_bounds__(256) void convert_kernel(
    const float* __restrict__ X, ushort_t* __restrict__ Xb)
{
    int i = (blockIdx.x * 256 + threadIdx.x) * 4;
    float4 v = *(const float4*)(X + i);
    ushort_t o[4] = { f2bf(v.x), f2bf(v.y), f2bf(v.z), f2bf(v.w) };
    *(uint2*)(Xb + i) = *(uint2*)o;
}

// ---------------------------------------------------------------------------
// W fp32 [2048][N] -> WT bf16 [N][2048] (transpose + convert), 64x64 tiles.
// ---------------------------------------------------------------------------
__global__ __launch_bounds__(256) void transpose_kernel(
    const float* __restrict__ W, ushort_t* __restrict__ WT, int N)
{
    __shared__ __align__(16) ushort_t tile[64][72];
    const int n0 = blockIdx.x * 64, k0 = blockIdx.y * 64;
    const int t = threadIdx.x;
    {
        const int tk = t >> 4;
        const int tn = (t & 15) * 4;
        #pragma unroll
        for (int i = 0; i < 4; i++) {
            const int k = tk + i * 16;
            float4 v = *(const float4*)(W + (size_t)(k0 + k) * N + n0 + tn);
            tile[tn + 0][k] = f2bf(v.x);
            tile[tn + 1][k] = f2bf(v.y);
            tile[tn + 2][k] = f2bf(v.z);
            tile[tn + 3][k] = f2bf(v.w);
        }
    }
    __syncthreads();
    {
        const int tn = t >> 2;
        const int tk = (t & 3) * 16;
        uint4 a = *(const uint4*)&tile[tn][tk];
        uint4 b = *(const uint4*)&tile[tn][tk + 8];
        ushort_t* dst = WT + (size_t)(n0 + tn) * DIM + k0 + tk;
        *(uint4*)dst = a;
        *(uint4*)(dst + 8) = b;
    }
}

// ---------------------------------------------------------------------------
// GEMM m97-style: C[M,N] = A[M,K](bf16) * BT[N,K](bf16)^T.
// 128x128 tile / 256 threads, BK=32, global_load_lds staging (unpadded LDS).
// Grid (N/128, M/128). OUT_F32: fp32 epilogue to d_out.
// ---------------------------------------------------------------------------
template<int OUT_F32>
__global__ __launch_bounds__(256) void gemm_kernel(
    const ushort_t* __restrict__ A, const ushort_t* __restrict__ BT,
    void* __restrict__ Cout, int K, int lda, int ldo)
{
    __shared__ __align__(16) ushort_t sA[128 * 32];
    __shared__ __align__(16) ushort_t sB[128 * 32];
    const int tn = blockIdx.x * 128, tm = blockIdx.y * 128;
    const int t = threadIdx.x, wave = t >> 6, lane = t & 63;
    const int m16 = lane & 15, quad = lane >> 4;
    const int wr = (wave >> 1) * 64, wc = (wave & 1) * 64;
    const int srow = lane >> 2;
    const int sce = (lane & 3) * 8;

    f32x4 acc[4][4] = {};

    for (int k0 = 0; k0 < K; k0 += 32) {
        __syncthreads();
        #pragma unroll
        for (int p = 0; p < 2; p++) {
            const int j = wave * 2 + p;
            const int row = j * 16 + srow;
            async_cp16(A  + (size_t)(tm + row) * lda + k0 + sce, &sA[j * 512]);
            async_cp16(BT + (size_t)(tn + row) * K   + k0 + sce, &sB[j * 512]);
        }
        __syncthreads();
        bf16x8 af[4], bf[4];
        #pragma unroll
        for (int mt = 0; mt < 4; mt++)
            af[mt] = *(const bf16x8*)&sA[(wr + mt * 16 + m16) * 32 + quad * 8];
        #pragma unroll
        for (int nt = 0; nt < 4; nt++)
            bf[nt] = *(const bf16x8*)&sB[(wc + nt * 16 + m16) * 32 + quad * 8];
        #pragma unroll
        for (int mt = 0; mt < 4; mt++)
            #pragma unroll
            for (int nt = 0; nt < 4; nt++)
                acc[mt][nt] = __builtin_amdgcn_mfma_f32_16x16x32_bf16(af[mt], bf[nt], acc[mt][nt], 0, 0, 0);
    }

    #pragma unroll
    for (int mt = 0; mt < 4; mt++) {
        const int row = tm + wr + mt * 16 + quad * 4;
        #pragma unroll
        for (int nt = 0; nt < 4; nt++) {
            const int col = tn + wc + nt * 16 + m16;
            #pragma unroll
            for (int r = 0; r < 4; r++) {
                if (OUT_F32)
                    ((float*)Cout)[(size_t)(row + r) * ldo + col] = acc[mt][nt][r];
                else
                    ((ushort_t*)Cout)[(size_t)(row + r) * ldo + col] = f2bf(acc[mt][nt][r]);
            }
        }
    }
}

// ---------------------------------------------------------------------------
// RoPE on one 64-elem head slice (thread owns whole slice).
// ---------------------------------------------------------------------------
__device__ inline void rope64(const ushort_t* src, ushort_t* dst, int s)
{
    uint4 w[8];
    #pragma unroll
    for (int t = 0; t < 8; t++) w[t] = *(const uint4*)(src + t * 8);
    ushort_t* u = (ushort_t*)w;
    float v[64], o[64];
    #pragma unroll
    for (int j = 0; j < 64; j++) v[j] = bf2f(u[j]);
    #pragma unroll
    for (int i = 0; i < 32; i++) {
        float freq = __expf(-(float)i * 0.28782313662425572f);  // ln(10000)/32
        float ang = (float)s * freq;
        float sv = sinf(ang), cv = cosf(ang);
        o[i]      = v[i]      * cv - v[2 * i + 1] * sv;
        o[i + 32] = v[i + 32] * cv + v[2 * i]     * sv;
    }
    #pragma unroll
    for (int j = 0; j < 64; j++) u[j] = f2bf(o[j]);
    #pragma unroll
    for (int t = 0; t < 8; t++) *(uint4*)(dst + t * 8) = w[t];
}

__global__ void rope_q_kernel(ushort_t* qkv)
{
    int gid = blockIdx.x * 256 + threadIdx.x;   // SEQ*NH
    int h = gid & 31, s = gid >> 5;
    ushort_t* p = qkv + (size_t)s * QKV_LD + h * 64;
    rope64(p, p, s);
}

__global__ void rope_k_kernel(const ushort_t* __restrict__ qkv, ushort_t* __restrict__ Kr)
{
    int gid = blockIdx.x * 256 + threadIdx.x;   // SEQ*NKV
    int kh = gid & 7, s = gid >> 3;
    rope64(qkv + (size_t)s * QKV_LD + 2048 + kh * 64,
           Kr + ((size_t)kh * SEQ + s) * 64, s);
}

// ---------------------------------------------------------------------------
// V transpose (tiled through LDS): Vt[kvh][d][s] = qkv[s][2560+kvh*64+d]
// ---------------------------------------------------------------------------
__global__ __launch_bounds__(256) void vtrans_kernel(
    const ushort_t* __restrict__ qkv, ushort_t* __restrict__ Vt)
{
    __shared__ __align__(16) ushort_t tile[64][72];
    const int kvh = blockIdx.x & 7;
    const int s0 = (blockIdx.x >> 3) * 64;
    const int t = threadIdx.x;
    {
        const int sr = t >> 3;
        const int d8 = (t & 7) * 8;
        #pragma unroll
        for (int i = 0; i < 2; i++) {
            const int s = sr + i * 32;
            ushort_t tmp[8];
            *(uint4*)tmp = *(const uint4*)(qkv + (size_t)(s0 + s) * QKV_LD + 2560 + kvh * 64 + d8);
            #pragma unroll
            for (int j = 0; j < 8; j++) tile[d8 + j][s] = tmp[j];
        }
    }
    __syncthreads();
    {
        const int dr = t >> 3;
        const int s8 = (t & 7) * 8;
        #pragma unroll
        for (int i = 0; i < 2; i++) {
            const int d = dr + i * 32;
            *(uint4*)(Vt + ((size_t)kvh * 64 + d) * SEQ + s0 + s8) = *(const uint4*)&tile[d][s8];
        }
    }
}

// ---------------------------------------------------------------------------
// Flash attention: block = (head, 128 queries), 4 waves x 2 q-tiles of 16.
// K/V 64-key tiles staged to LDS via global_load_lds, shared by all waves.
// Per-wave bf16 sP round-trip (C-layout -> A-layout) with wave-local fences.
// Output overwrites qkv q-region (each wave writes exactly the rows it read).
// Grid: NH * (SEQ/128) = 512.
// ---------------------------------------------------------------------------
__global__ __launch_bounds__(256) void attn_kernel(
    ushort_t* qkv, const ushort_t* __restrict__ Kr, const ushort_t* __restrict__ Vt)
{
    __shared__ __align__(16) ushort_t sK[64 * 64];   // [key][d]
    __shared__ __align__(16) ushort_t sV[64 * 64];   // [d][key]
    __shared__ __align__(16) ushort_t sP[4][16 * 72];

    const int t = threadIdx.x, wave = t >> 6, lane = t & 63;
    const int m16 = lane & 15, quad = lane >> 4;
    const int h = blockIdx.x >> 4;
    const int qbt = blockIdx.x & 15;
    const int qb = qbt * 128;
    const int kvh = h >> 2;

    const ushort_t* Krh = Kr + (size_t)kvh * SEQ * 64;
    const ushort_t* Vth = Vt + (size_t)kvh * 64 * SEQ;

    bf16x8 qf[2][2];
    #pragma unroll
    for (int qa = 0; qa < 2; qa++) {
        const int q0 = qb + (wave + qa * 4) * 16;
        const ushort_t* qp = qkv + (size_t)(q0 + m16) * QKV_LD + h * 64 + quad * 8;
        qf[qa][0] = *(const bf16x8*)qp;
        qf[qa][1] = *(const bf16x8*)(qp + 32);
    }

    f32x4 oacc[2][4] = {};
    float m_run[2][4], l_run[2][4];
    #pragma unroll
    for (int qa = 0; qa < 2; qa++)
        #pragma unroll
        for (int r = 0; r < 4; r++) { m_run[qa][r] = -1e30f; l_run[qa][r] = 0.f; }

    ushort_t* sPw = sP[wave];
    const int nkt = qbt * 2 + 2;

    for (int kt = 0; kt < nkt; kt++) {
        const int kbase = kt * 64;
        const bool domask = (kt >= nkt - 2);

        __syncthreads();
        #pragma unroll
        for (int p = 0; p < 2; p++) {
            const int j = wave * 2 + p;
            async_cp16(Krh + (size_t)kbase * 64 + j * 512 + lane * 8, &sK[j * 512]);
            const int d = j * 8 + (lane >> 3);
            async_cp16(Vth + (size_t)d * SEQ + kbase + (lane & 7) * 8, &sV[j * 512]);
        }
        __syncthreads();

        bf16x8 vf[4][2];
        #pragma unroll
        for (int nt = 0; nt < 4; nt++)
            #pragma unroll
            for (int kk = 0; kk < 2; kk++)
                vf[nt][kk] = *(const bf16x8*)&sV[(nt * 16 + m16) * 64 + kk * 32 + quad * 8];

        #pragma unroll
        for (int qa = 0; qa < 2; qa++) {
            const int qrow0 = qb + (wave + qa * 4) * 16 + quad * 4;

            f32x4 sc[4] = {};
            #pragma unroll
            for (int knt = 0; knt < 4; knt++) {
                bf16x8 kf0 = *(const bf16x8*)&sK[(knt * 16 + m16) * 64 + quad * 8];
                bf16x8 kf1 = *(const bf16x8*)&sK[(knt * 16 + m16) * 64 + 32 + quad * 8];
                sc[knt] = __builtin_amdgcn_mfma_f32_16x16x32_bf16(qf[qa][0], kf0, sc[knt], 0, 0, 0);
                sc[knt] = __builtin_amdgcn_mfma_f32_16x16x32_bf16(qf[qa][1], kf1, sc[knt], 0, 0, 0);
            }

            float alpha[4];
            float pv[4][4];
            #pragma unroll
            for (int r = 0; r < 4; r++) {
                const int qi = qrow0 + r;
                float s0 = sc[0][r] * 0.125f;
                float s1 = sc[1][r] * 0.125f;
                float s2 = sc[2][r] * 0.125f;
                float s3 = sc[3][r] * 0.125f;
                if (domask) {
                    if (kbase +      m16 > qi) s0 = -1e30f;
                    if (kbase + 16 + m16 > qi) s1 = -1e30f;
                    if (kbase + 32 + m16 > qi) s2 = -1e30f;
                    if (kbase + 48 + m16 > qi) s3 = -1e30f;
                }
                float rmax = fmaxf(fmaxf(s0, s1), fmaxf(s2, s3));
                #pragma unroll
                for (int off = 1; off < 16; off <<= 1)
                    rmax = fmaxf(rmax, __shfl_xor(rmax, off, 64));
                const float mnew = fmaxf(m_run[qa][r], rmax);
                alpha[r] = __expf(m_run[qa][r] - mnew);
                m_run[qa][r] = mnew;
                const float p0 = __expf(s0 - mnew), p1 = __expf(s1 - mnew);
                const float p2 = __expf(s2 - mnew), p3 = __expf(s3 - mnew);
                pv[r][0] = p0; pv[r][1] = p1; pv[r][2] = p2; pv[r][3] = p3;
                float ps = p0 + p1 + p2 + p3;
                #pragma unroll
                for (int off = 1; off < 16; off <<= 1)
                    ps += __shfl_xor(ps, off, 64);
                l_run[qa][r] = l_run[qa][r] * alpha[r] + ps;
            }

            lgkm_fence();   // prior sP reads (prev qa/tile) complete before overwrite
            #pragma unroll
            for (int r = 0; r < 4; r++)
                #pragma unroll
                for (int knt = 0; knt < 4; knt++)
                    sPw[(quad * 4 + r) * 72 + knt * 16 + m16] = f2bf(pv[r][knt]);
            lgkm_fence();   // writes visible before reads

            bf16x8 pf[2];
            pf[0] = *(const bf16x8*)&sPw[m16 * 72 + quad * 8];
            pf[1] = *(const bf16x8*)&sPw[m16 * 72 + 32 + quad * 8];

            #pragma unroll
            for (int nt = 0; nt < 4; nt++) {
                #pragma unroll
                for (int r = 0; r < 4; r++) oacc[qa][nt][r] *= alpha[r];
                oacc[qa][nt] = __builtin_amdgcn_mfma_f32_16x16x32_bf16(pf[0], vf[nt][0], oacc[qa][nt], 0, 0, 0);
                oacc[qa][nt] = __builtin_amdgcn_mfma_f32_16x16x32_bf16(pf[1], vf[nt][1], oacc[qa][nt], 0, 0, 0);
            }
        }
    }

    #pragma unroll
    for (int qa = 0; qa < 2; qa++) {
        const int qrow0 = qb + (wave + qa * 4) * 16 + quad * 4;
        #pragma unroll
        for (int nt = 0; nt < 4; nt++) {
            const int col = h * 64 + nt * 16 + m16;
            #pragma unroll
            for (int r = 0; r < 4; r++)
                qkv[(size_t)(qrow0 + r) * QKV_LD + col] = f2bf(oacc[qa][nt][r] / l_run[qa][r]);
        }
    }
}

// ---------------------------------------------------------------------------
extern "C" void kernel_launch(void* const* d_in, const int* in_sizes, int n_in,
                              void* d_out, int out_size, void* d_ws, size_t ws_size,
                              hipStream_t stream)
{
    const float* x  = (const float*)d_in[0];
    // d_in[1] = mask (int32) — causal, handled analytically
    const float* wq = (const float*)d_in[2];
    const float* wk = (const float*)d_in[3];
    const float* wv = (const float*)d_in[4];
    const float* wo = (const float*)d_in[5];

    ushort_t* WT  = (ushort_t*)d_ws;                    // [3072][2048] bf16, 12.58 MB
    ushort_t* xb  = WT + (size_t)3072 * 2048;           // [2048][2048] bf16, 8.39 MB
    ushort_t* woT = xb;                                 // alias: xb dead after QKV GEMM
    ushort_t* qkv = xb + (size_t)2048 * 2048;           // [2048][3072] bf16, 12.58 MB
    ushort_t* Kr  = qkv + (size_t)SEQ * QKV_LD;         // [8][2048][64], 2.10 MB
    ushort_t* Vt  = Kr + (size_t)NKV * SEQ * HD;        // [8][64][2048], 2.10 MB
    // total ws ≈ 37.75 MB

    dim3 blk(256);

    convert_kernel<<<(DIM * SEQ) / 1024, blk, 0, stream>>>(x, xb);
    transpose_kernel<<<dim3(32, 32), blk, 0, stream>>>(wq, WT, 2048);
    transpose_kernel<<<dim3(8, 32),  blk, 0, stream>>>(wk, WT + (size_t)2048 * 2048, 512);
    transpose_kernel<<<dim3(8, 32),  blk, 0, stream>>>(wv, WT + (size_t)2560 * 2048, 512);

    // Fused QKV projection: [2048,2048] x [2048,3072] -> qkv
    gemm_kernel<0><<<dim3(QKV_LD / 128, SEQ / 128), blk, 0, stream>>>(xb, WT, qkv, DIM, DIM, QKV_LD);

    // wo transpose (reuses xb region — must follow the QKV GEMM)
    transpose_kernel<<<dim3(32, 32), blk, 0, stream>>>(wo, woT, 2048);

    rope_q_kernel<<<(SEQ * NH) / 256, blk, 0, stream>>>(qkv);
    rope_k_kernel<<<(SEQ * NKV) / 256, blk, 0, stream>>>(qkv, Kr);
    vtrans_kernel<<<NKV * (SEQ / 64), blk, 0, stream>>>(qkv, Vt);

    attn_kernel<<<NH * (SEQ / 128), blk, 0, stream>>>(qkv, Kr, Vt);

    // Output projection -> d_out fp32
    gemm_kernel<1><<<dim3(DIM / 128, SEQ / 128), blk, 0, stream>>>(qkv, woT, d_out, DIM, QKV_LD, DIM);
}

// Round 6
// 357.352 us; speedup vs baseline: 2.1587x; 1.2008x over previous
//
#include <hip/hip_runtime.h>
#include <hip/hip_bf16.h>

#define DIM 2048
#define SEQ 2048
#define NH 32
#define HD 64
#define NKV 8
#define QKV_LD 3072

typedef __attribute__((ext_vector_type(8))) short bf16x8;
typedef __attribute__((ext_vector_type(4))) float f32x4;
typedef unsigned short ushort_t;

__device__ inline unsigned short f2bf(float f) {
    union { float f; unsigned int u; } v; v.f = f;
    unsigned int r = v.u + 0x7fffu + ((v.u >> 16) & 1u);
    return (unsigned short)(r >> 16);
}
__device__ inline float bf2f(ushort_t u) {
    union { unsigned int u; float f; } v; v.u = ((unsigned int)u) << 16; return v.f;
}

// async global->LDS, 16B per lane. LDS dest is wave-uniform base + lane*16.
__device__ inline void async_cp16(const void* g, void* l) {
    __builtin_amdgcn_global_load_lds(
        (const __attribute__((address_space(1))) unsigned int*)g,
        (__attribute__((address_space(3))) unsigned int*)l, 16, 0, 0);
}
__device__ inline void lgkm_fence() {
    __asm__ volatile("s_waitcnt lgkmcnt(0)" ::: "memory");
}

// ---------------------------------------------------------------------------
// x fp32 -> bf16 (4 elems/thread)
// ---------------------------------------------------------------------------
__global__ __launch_bounds__(256) void convert_kernel(
    const float* __restrict__ X, ushort_t* __restrict__ Xb)
{
    int i = (blockIdx.x * 256 + threadIdx.x) * 4;
    float4 v = *(const float4*)(X + i);
    ushort_t o[4] = { f2bf(v.x), f2bf(v.y), f2bf(v.z), f2bf(v.w) };
    *(uint2*)(Xb + i) = *(uint2*)o;
}

// ---------------------------------------------------------------------------
// W fp32 [2048][N] -> WT bf16 [N][2048] (transpose + convert), 64x64 tiles.
// ---------------------------------------------------------------------------
__global__ __launch_bounds__(256) void transpose_kernel(
    const float* __restrict__ W, ushort_t* __restrict__ WT, int N)
{
    __shared__ __align__(16) ushort_t tile[64][72];
    const int n0 = blockIdx.x * 64, k0 = blockIdx.y * 64;
    const int t = threadIdx.x;
    {
        const int tk = t >> 4;
        const int tn = (t & 15) * 4;
        #pragma unroll
        for (int i = 0; i < 4; i++) {
            const int k = tk + i * 16;
            float4 v = *(const float4*)(W + (size_t)(k0 + k) * N + n0 + tn);
            tile[tn + 0][k] = f2bf(v.x);
            tile[tn + 1][k] = f2bf(v.y);
            tile[tn + 2][k] = f2bf(v.z);
            tile[tn + 3][k] = f2bf(v.w);
        }
    }
    __syncthreads();
    {
        const int tn = t >> 2;
        const int tk = (t & 3) * 16;
        uint4 a = *(const uint4*)&tile[tn][tk];
        uint4 b = *(const uint4*)&tile[tn][tk + 8];
        ushort_t* dst = WT + (size_t)(n0 + tn) * DIM + k0 + tk;
        *(uint4*)dst = a;
        *(uint4*)(dst + 8) = b;
    }
}

// ---------------------------------------------------------------------------
// GEMM m97-style: C[M,N] = A[M,K](bf16) * BT[N,K](bf16)^T.
// 128x128 tile / 256 threads, BK=32, global_load_lds staging (unpadded LDS).
// Grid (N/128, M/128). OUT_F32: fp32 epilogue to d_out.
// ---------------------------------------------------------------------------
template<int OUT_F32>
__global__ __launch_bounds__(256) void gemm_kernel(
    const ushort_t* __restrict__ A, const ushort_t* __restrict__ BT,
    void* __restrict__ Cout, int K, int lda, int ldo)
{
    __shared__ __align__(16) ushort_t sA[128 * 32];
    __shared__ __align__(16) ushort_t sB[128 * 32];
    const int tn = blockIdx.x * 128, tm = blockIdx.y * 128;
    const int t = threadIdx.x, wave = t >> 6, lane = t & 63;
    const int m16 = lane & 15, quad = lane >> 4;
    const int wr = (wave >> 1) * 64, wc = (wave & 1) * 64;
    const int srow = lane >> 2;
    const int sce = (lane & 3) * 8;

    f32x4 acc[4][4] = {};

    for (int k0 = 0; k0 < K; k0 += 32) {
        __syncthreads();
        #pragma unroll
        for (int p = 0; p < 2; p++) {
            const int j = wave * 2 + p;
            const int row = j * 16 + srow;
            async_cp16(A  + (size_t)(tm + row) * lda + k0 + sce, &sA[j * 512]);
            async_cp16(BT + (size_t)(tn + row) * K   + k0 + sce, &sB[j * 512]);
        }
        __syncthreads();
        bf16x8 af[4], bf[4];
        #pragma unroll
        for (int mt = 0; mt < 4; mt++)
            af[mt] = *(const bf16x8*)&sA[(wr + mt * 16 + m16) * 32 + quad * 8];
        #pragma unroll
        for (int nt = 0; nt < 4; nt++)
            bf[nt] = *(const bf16x8*)&sB[(wc + nt * 16 + m16) * 32 + quad * 8];
        #pragma unroll
        for (int mt = 0; mt < 4; mt++)
            #pragma unroll
            for (int nt = 0; nt < 4; nt++)
                acc[mt][nt] = __builtin_amdgcn_mfma_f32_16x16x32_bf16(af[mt], bf[nt], acc[mt][nt], 0, 0, 0);
    }

    #pragma unroll
    for (int mt = 0; mt < 4; mt++) {
        const int row = tm + wr + mt * 16 + quad * 4;
        #pragma unroll
        for (int nt = 0; nt < 4; nt++) {
            const int col = tn + wc + nt * 16 + m16;
            #pragma unroll
            for (int r = 0; r < 4; r++) {
                if (OUT_F32)
                    ((float*)Cout)[(size_t)(row + r) * ldo + col] = acc[mt][nt][r];
                else
                    ((ushort_t*)Cout)[(size_t)(row + r) * ldo + col] = f2bf(acc[mt][nt][r]);
            }
        }
    }
}

// ---------------------------------------------------------------------------
// RoPE on one 64-elem head slice (thread owns whole slice).
// ---------------------------------------------------------------------------
__device__ inline void rope64(const ushort_t* src, ushort_t* dst, int s)
{
    uint4 w[8];
    #pragma unroll
    for (int t = 0; t < 8; t++) w[t] = *(const uint4*)(src + t * 8);
    ushort_t* u = (ushort_t*)w;
    float v[64], o[64];
    #pragma unroll
    for (int j = 0; j < 64; j++) v[j] = bf2f(u[j]);
    #pragma unroll
    for (int i = 0; i < 32; i++) {
        float freq = __expf(-(float)i * 0.28782313662425572f);  // ln(10000)/32
        float ang = (float)s * freq;
        float sv = sinf(ang), cv = cosf(ang);
        o[i]      = v[i]      * cv - v[2 * i + 1] * sv;
        o[i + 32] = v[i + 32] * cv + v[2 * i]     * sv;
    }
    #pragma unroll
    for (int j = 0; j < 64; j++) u[j] = f2bf(o[j]);
    #pragma unroll
    for (int t = 0; t < 8; t++) *(uint4*)(dst + t * 8) = w[t];
}

// Fused RoPE for Q (in place) and K (into Kr[kvh][s][64]).
__global__ void rope_kernel(ushort_t* qkv, ushort_t* __restrict__ Kr)
{
    int gid = blockIdx.x * 256 + threadIdx.x;   // SEQ*(NH+NKV)
    if (gid < SEQ * NH) {
        int h = gid & 31, s = gid >> 5;
        ushort_t* p = qkv + (size_t)s * QKV_LD + h * 64;
        rope64(p, p, s);
    } else {
        int g2 = gid - SEQ * NH;
        int kh = g2 & 7, s = g2 >> 3;
        rope64(qkv + (size_t)s * QKV_LD + 2048 + kh * 64,
               Kr + ((size_t)kh * SEQ + s) * 64, s);
    }
}

// ---------------------------------------------------------------------------
// V transpose (tiled through LDS): Vt[kvh][d][s] = qkv[s][2560+kvh*64+d]
// ---------------------------------------------------------------------------
__global__ __launch_bounds__(256) void vtrans_kernel(
    const ushort_t* __restrict__ qkv, ushort_t* __restrict__ Vt)
{
    __shared__ __align__(16) ushort_t tile[64][72];
    const int kvh = blockIdx.x & 7;
    const int s0 = (blockIdx.x >> 3) * 64;
    const int t = threadIdx.x;
    {
        const int sr = t >> 3;
        const int d8 = (t & 7) * 8;
        #pragma unroll
        for (int i = 0; i < 2; i++) {
            const int s = sr + i * 32;
            ushort_t tmp[8];
            *(uint4*)tmp = *(const uint4*)(qkv + (size_t)(s0 + s) * QKV_LD + 2560 + kvh * 64 + d8);
            #pragma unroll
            for (int j = 0; j < 8; j++) tile[d8 + j][s] = tmp[j];
        }
    }
    __syncthreads();
    {
        const int dr = t >> 3;
        const int s8 = (t & 7) * 8;
        #pragma unroll
        for (int i = 0; i < 2; i++) {
            const int d = dr + i * 32;
            *(uint4*)(Vt + ((size_t)kvh * 64 + d) * SEQ + s0 + s8) = *(const uint4*)&tile[d][s8];
        }
    }
}

// ---------------------------------------------------------------------------
// Flash attention, S^T orientation (S^T = K @ Q^T; O^T = V^T @ P^T).
// Block = (head, 128 queries), 4 waves x 2 q-tiles of 16; NO block barriers.
// K/V fragments read directly from L2-resident Kr/Vt; P^T transposed through
// per-wave LDS (4x ds_write_b64 + 2x ds_read_b128). Heavy blocks launch first.
// Grid: 16 * NH; blockIdx = qrev*NH + h, qbt = 15 - qrev.
// ---------------------------------------------------------------------------
#define SPS 80   // sP row stride (ushorts), 16 q-rows x 64 keys + pad
__global__ __launch_bounds__(256) void attn_kernel(
    ushort_t* qkv, const ushort_t* __restrict__ Kr, const ushort_t* __restrict__ Vt)
{
    __shared__ __align__(16) ushort_t sP[4][16 * SPS];

    const int t = threadIdx.x, wave = t >> 6, lane = t & 63;
    const int m16 = lane & 15, quad = lane >> 4;
    const int h = blockIdx.x & 31;
    const int qbt = 15 - (blockIdx.x >> 5);    // heavy first
    const int qb = qbt * 128;
    const int kvh = h >> 2;

    const ushort_t* Krh = Kr + (size_t)kvh * SEQ * 64;   // [s][d]
    const ushort_t* Vth = Vt + (size_t)kvh * 64 * SEQ;   // [d][s]

    // Q fragments (B-operand layout = same as A): rows q0+m16, d = quad*8+j
    bf16x8 qf[2][2];
    #pragma unroll
    for (int qa = 0; qa < 2; qa++) {
        const int q0 = qb + (wave + qa * 4) * 16;
        const ushort_t* qp = qkv + (size_t)(q0 + m16) * QKV_LD + h * 64 + quad * 8;
        qf[qa][0] = *(const bf16x8*)qp;
        qf[qa][1] = *(const bf16x8*)(qp + 32);
    }

    f32x4 oacc[2][4] = {};                  // O^T: col=q(m16), row=d(quad*4+r), nt = d/16
    float m_run[2] = { -1e30f, -1e30f };    // per-q scalars (q = m16)
    float l_run[2] = { 0.f, 0.f };

    ushort_t* sPw = sP[wave];
    const int nkt = qbt * 2 + 2;

    for (int kt = 0; kt < nkt; kt++) {
        const int kbase = kt * 64;
        const bool domask = (kt >= nkt - 2);

        // K fragments: A[m=key(m16)][k=d]; V^T fragments: A[m=d(m16)][k=key]
        bf16x8 kf[4][2], vf[4][2];
        #pragma unroll
        for (int knt = 0; knt < 4; knt++) {
            const ushort_t* kp = Krh + (size_t)(kbase + knt * 16 + m16) * 64 + quad * 8;
            kf[knt][0] = *(const bf16x8*)kp;
            kf[knt][1] = *(const bf16x8*)(kp + 32);
        }
        #pragma unroll
        for (int nt = 0; nt < 4; nt++) {
            const ushort_t* vp = Vth + (size_t)(nt * 16 + m16) * SEQ + kbase + quad * 8;
            vf[nt][0] = *(const bf16x8*)vp;
            vf[nt][1] = *(const bf16x8*)(vp + 32);
        }

        #pragma unroll
        for (int qa = 0; qa < 2; qa++) {
            const int qi = qb + (wave + qa * 4) * 16 + m16;   // this lane's query

            // S^T tiles: sc[knt][r] = S[q=m16][key = kbase+knt*16+quad*4+r]
            f32x4 sc[4] = {};
            #pragma unroll
            for (int knt = 0; knt < 4; knt++) {
                sc[knt] = __builtin_amdgcn_mfma_f32_16x16x32_bf16(kf[knt][0], qf[qa][0], sc[knt], 0, 0, 0);
                sc[knt] = __builtin_amdgcn_mfma_f32_16x16x32_bf16(kf[knt][1], qf[qa][1], sc[knt], 0, 0, 0);
            }

            float s[16];
            #pragma unroll
            for (int knt = 0; knt < 4; knt++)
                #pragma unroll
                for (int r = 0; r < 4; r++) {
                    float v = sc[knt][r] * 0.125f;
                    if (domask && (kbase + knt * 16 + quad * 4 + r > qi)) v = -1e30f;
                    s[knt * 4 + r] = v;
                }

            float rmax = s[0];
            #pragma unroll
            for (int i = 1; i < 16; i++) rmax = fmaxf(rmax, s[i]);
            rmax = fmaxf(rmax, __shfl_xor(rmax, 16, 64));
            rmax = fmaxf(rmax, __shfl_xor(rmax, 32, 64));

            const float mnew = fmaxf(m_run[qa], rmax);
            const float alpha = __expf(m_run[qa] - mnew);
            m_run[qa] = mnew;

            float ps = 0.f;
            #pragma unroll
            for (int i = 0; i < 16; i++) { s[i] = __expf(s[i] - mnew); ps += s[i]; }
            ps += __shfl_xor(ps, 16, 64);
            ps += __shfl_xor(ps, 32, 64);
            l_run[qa] = l_run[qa] * alpha + ps;

            // ---- P^T -> LDS (col-major sP[q][key]), packed b64 writes ----
            lgkm_fence();   // WAR: prior pf reads complete
            #pragma unroll
            for (int knt = 0; knt < 4; knt++) {
                unsigned int u0 = (unsigned int)f2bf(s[knt * 4 + 0]) | ((unsigned int)f2bf(s[knt * 4 + 1]) << 16);
                unsigned int u1 = (unsigned int)f2bf(s[knt * 4 + 2]) | ((unsigned int)f2bf(s[knt * 4 + 3]) << 16);
                uint2 pk; pk.x = u0; pk.y = u1;
                *(uint2*)&sPw[m16 * SPS + knt * 16 + quad * 4] = pk;
            }
            lgkm_fence();   // writes visible before reads
            bf16x8 pf0 = *(const bf16x8*)&sPw[m16 * SPS + quad * 8];
            bf16x8 pf1 = *(const bf16x8*)&sPw[m16 * SPS + 32 + quad * 8];

            // ---- O^T += V^T @ P^T ----
            #pragma unroll
            for (int nt = 0; nt < 4; nt++) {
                #pragma unroll
                for (int r = 0; r < 4; r++) oacc[qa][nt][r] *= alpha;
                oacc[qa][nt] = __builtin_amdgcn_mfma_f32_16x16x32_bf16(vf[nt][0], pf0, oacc[qa][nt], 0, 0, 0);
                oacc[qa][nt] = __builtin_amdgcn_mfma_f32_16x16x32_bf16(vf[nt][1], pf1, oacc[qa][nt], 0, 0, 0);
            }
        }
    }

    // ---- epilogue: O[q][h*64+d] = O^T/l, 4 consecutive d per lane -> b64 ----
    #pragma unroll
    for (int qa = 0; qa < 2; qa++) {
        const int q = qb + (wave + qa * 4) * 16 + m16;
        const float rl = 1.f / l_run[qa];
        #pragma unroll
        for (int nt = 0; nt < 4; nt++) {
            ushort_t pk[4];
            #pragma unroll
            for (int r = 0; r < 4; r++) pk[r] = f2bf(oacc[qa][nt][r] * rl);
            *(uint2*)&qkv[(size_t)q * QKV_LD + h * 64 + nt * 16 + quad * 4] = *(uint2*)pk;
        }
    }
}

// ---------------------------------------------------------------------------
extern "C" void kernel_launch(void* const* d_in, const int* in_sizes, int n_in,
                              void* d_out, int out_size, void* d_ws, size_t ws_size,
                              hipStream_t stream)
{
    const float* x  = (const float*)d_in[0];
    // d_in[1] = mask (int32) — causal, handled analytically
    const float* wq = (const float*)d_in[2];
    const float* wk = (const float*)d_in[3];
    const float* wv = (const float*)d_in[4];
    const float* wo = (const float*)d_in[5];

    ushort_t* WT  = (ushort_t*)d_ws;                    // [3072][2048] bf16
    ushort_t* xb  = WT + (size_t)3072 * 2048;           // [2048][2048] bf16
    ushort_t* woT = xb;                                 // alias: xb dead after QKV GEMM
    ushort_t* qkv = xb + (size_t)2048 * 2048;           // [2048][3072] bf16
    ushort_t* Kr  = qkv + (size_t)SEQ * QKV_LD;         // [8][2048][64]
    ushort_t* Vt  = Kr + (size_t)NKV * SEQ * HD;        // [8][64][2048]

    dim3 blk(256);

    convert_kernel<<<(DIM * SEQ) / 1024, blk, 0, stream>>>(x, xb);
    transpose_kernel<<<dim3(32, 32), blk, 0, stream>>>(wq, WT, 2048);
    transpose_kernel<<<dim3(8, 32),  blk, 0, stream>>>(wk, WT + (size_t)2048 * 2048, 512);
    transpose_kernel<<<dim3(8, 32),  blk, 0, stream>>>(wv, WT + (size_t)2560 * 2048, 512);

    // Fused QKV projection: [2048,2048] x [2048,3072] -> qkv
    gemm_kernel<0><<<dim3(QKV_LD / 128, SEQ / 128), blk, 0, stream>>>(xb, WT, qkv, DIM, DIM, QKV_LD);

    // wo transpose (reuses xb region — must follow the QKV GEMM)
    transpose_kernel<<<dim3(32, 32), blk, 0, stream>>>(wo, woT, 2048);

    rope_kernel<<<(SEQ * (NH + NKV)) / 256, blk, 0, stream>>>(qkv, Kr);
    vtrans_kernel<<<NKV * (SEQ / 64), blk, 0, stream>>>(qkv, Vt);

    attn_kernel<<<16 * NH, blk, 0, stream>>>(qkv, Kr, Vt);

    // Output projection -> d_out fp32
    gemm_kernel<1><<<dim3(DIM / 128, SEQ / 128), blk, 0, stream>>>(qkv, woT, d_out, DIM, QKV_LD, DIM);
}

// Round 7
// 315.045 us; speedup vs baseline: 2.4486x; 1.1343x over previous
//
#include <hip/hip_runtime.h>
#include <hip/hip_bf16.h>

#define DIM 2048
#define SEQ 2048
#define NH 32
#define HD 64
#define NKV 8
#define QKV_LD 3072

typedef __attribute__((ext_vector_type(8))) short bf16x8;
typedef __attribute__((ext_vector_type(4))) float f32x4;
typedef unsigned short ushort_t;

__device__ inline unsigned short f2bf(float f) {
    union { float f; unsigned int u; } v; v.f = f;
    unsigned int r = v.u + 0x7fffu + ((v.u >> 16) & 1u);
    return (unsigned short)(r >> 16);
}
__device__ inline float bf2f(ushort_t u) {
    union { unsigned int u; float f; } v; v.u = ((unsigned int)u) << 16; return v.f;
}

// async global->LDS, 16B per lane. LDS dest is wave-uniform base + lane*16.
__device__ inline void async_cp16(const void* g, void* l) {
    __builtin_amdgcn_global_load_lds(
        (const __attribute__((address_space(1))) unsigned int*)g,
        (__attribute__((address_space(3))) unsigned int*)l, 16, 0, 0);
}
__device__ inline void lgkm_fence() {
    __asm__ volatile("s_waitcnt lgkmcnt(0)" ::: "memory");
}

// ---------------------------------------------------------------------------
// x fp32 -> bf16 (4 elems/thread)
// ---------------------------------------------------------------------------
__global__ __launch_bounds__(256) void convert_kernel(
    const float* __restrict__ X, ushort_t* __restrict__ Xb)
{
    int i = (blockIdx.x * 256 + threadIdx.x) * 4;
    float4 v = *(const float4*)(X + i);
    ushort_t o[4] = { f2bf(v.x), f2bf(v.y), f2bf(v.z), f2bf(v.w) };
    *(uint2*)(Xb + i) = *(uint2*)o;
}

// ---------------------------------------------------------------------------
// W fp32 [2048][N] -> WT bf16 [N][2048] (transpose + convert), 64x64 tiles.
// ---------------------------------------------------------------------------
__global__ __launch_bounds__(256) void transpose_kernel(
    const float* __restrict__ W, ushort_t* __restrict__ WT, int N)
{
    __shared__ __align__(16) ushort_t tile[64][72];
    const int n0 = blockIdx.x * 64, k0 = blockIdx.y * 64;
    const int t = threadIdx.x;
    {
        const int tk = t >> 4;
        const int tn = (t & 15) * 4;
        #pragma unroll
        for (int i = 0; i < 4; i++) {
            const int k = tk + i * 16;
            float4 v = *(const float4*)(W + (size_t)(k0 + k) * N + n0 + tn);
            tile[tn + 0][k] = f2bf(v.x);
            tile[tn + 1][k] = f2bf(v.y);
            tile[tn + 2][k] = f2bf(v.z);
            tile[tn + 3][k] = f2bf(v.w);
        }
    }
    __syncthreads();
    {
        const int tn = t >> 2;
        const int tk = (t & 3) * 16;
        uint4 a = *(const uint4*)&tile[tn][tk];
        uint4 b = *(const uint4*)&tile[tn][tk + 8];
        ushort_t* dst = WT + (size_t)(n0 + tn) * DIM + k0 + tk;
        *(uint4*)dst = a;
        *(uint4*)(dst + 8) = b;
    }
}

// ---------------------------------------------------------------------------
// GEMM m97-style: C[M,N] = A[M,K](bf16) * BT[N,K](bf16)^T.
// 128x128 tile / 256 threads, BK=32, global_load_lds staging (unpadded LDS).
// Grid (N/128, M/128). OUT_F32: fp32 epilogue to d_out.
// ---------------------------------------------------------------------------
template<int OUT_F32>
__global__ __launch_bounds__(256) void gemm_kernel(
    const ushort_t* __restrict__ A, const ushort_t* __restrict__ BT,
    void* __restrict__ Cout, int K, int lda, int ldo)
{
    __shared__ __align__(16) ushort_t sA[128 * 32];
    __shared__ __align__(16) ushort_t sB[128 * 32];
    const int tn = blockIdx.x * 128, tm = blockIdx.y * 128;
    const int t = threadIdx.x, wave = t >> 6, lane = t & 63;
    const int m16 = lane & 15, quad = lane >> 4;
    const int wr = (wave >> 1) * 64, wc = (wave & 1) * 64;
    const int srow = lane >> 2;
    const int sce = (lane & 3) * 8;

    f32x4 acc[4][4] = {};

    for (int k0 = 0; k0 < K; k0 += 32) {
        __syncthreads();
        #pragma unroll
        for (int p = 0; p < 2; p++) {
            const int j = wave * 2 + p;
            const int row = j * 16 + srow;
            async_cp16(A  + (size_t)(tm + row) * lda + k0 + sce, &sA[j * 512]);
            async_cp16(BT + (size_t)(tn + row) * K   + k0 + sce, &sB[j * 512]);
        }
        __syncthreads();
        bf16x8 af[4], bf[4];
        #pragma unroll
        for (int mt = 0; mt < 4; mt++)
            af[mt] = *(const bf16x8*)&sA[(wr + mt * 16 + m16) * 32 + quad * 8];
        #pragma unroll
        for (int nt = 0; nt < 4; nt++)
            bf[nt] = *(const bf16x8*)&sB[(wc + nt * 16 + m16) * 32 + quad * 8];
        #pragma unroll
        for (int mt = 0; mt < 4; mt++)
            #pragma unroll
            for (int nt = 0; nt < 4; nt++)
                acc[mt][nt] = __builtin_amdgcn_mfma_f32_16x16x32_bf16(af[mt], bf[nt], acc[mt][nt], 0, 0, 0);
    }

    #pragma unroll
    for (int mt = 0; mt < 4; mt++) {
        const int row = tm + wr + mt * 16 + quad * 4;
        #pragma unroll
        for (int nt = 0; nt < 4; nt++) {
            const int col = tn + wc + nt * 16 + m16;
            #pragma unroll
            for (int r = 0; r < 4; r++) {
                if (OUT_F32)
                    ((float*)Cout)[(size_t)(row + r) * ldo + col] = acc[mt][nt][r];
                else
                    ((ushort_t*)Cout)[(size_t)(row + r) * ldo + col] = f2bf(acc[mt][nt][r]);
            }
        }
    }
}

// ---------------------------------------------------------------------------
// RoPE, lane-per-element: one wave per 64-elem head slice, 1 shuffle/lane.
// lane l<32:  out = e[l]*cos(ang_l)      - e[2l+1]*sin(ang_l)
// lane l>=32: out = e[l]*cos(ang_{l-32}) + e[2(l-32)]*sin(ang_{l-32})
// Slices: idx in [0, SEQ*40): hh<32 -> Q (in place), else K -> Kr[kvh][s][64].
// ---------------------------------------------------------------------------
__global__ __launch_bounds__(256) void rope_kernel(ushort_t* qkv, ushort_t* __restrict__ Kr)
{
    const int gid = blockIdx.x * 256 + threadIdx.x;
    const int lane = gid & 63;
    const int idx = gid >> 6;              // slice index
    const int s = idx / 40;
    const int hh = idx - s * 40;

    const ushort_t* src;
    ushort_t* dst;
    if (hh < 32) {
        dst = qkv + (size_t)s * QKV_LD + hh * 64;
        src = dst;
    } else {
        src = qkv + (size_t)s * QKV_LD + 2048 + (hh - 32) * 64;
        dst = Kr + ((size_t)(hh - 32) * SEQ + s) * 64;
    }

    const float e = bf2f(src[lane]);
    const int i = lane & 31;
    const float freq = __expf(-(float)i * 0.28782313662425572f);  // ln(10000)/32
    const float ang = (float)s * freq;
    const float cv = cosf(ang), sv = sinf(ang);
    const int partner = (lane < 32) ? (2 * lane + 1) : (2 * (lane - 32));
    const float y = __shfl(e, partner, 64);
    const float out = (lane < 32) ? (e * cv - y * sv) : (e * cv + y * sv);
    dst[lane] = f2bf(out);
}

// ---------------------------------------------------------------------------
// V transpose (tiled through LDS): Vt[kvh][d][s] = qkv[s][2560+kvh*64+d]
// ---------------------------------------------------------------------------
__global__ __launch_bounds__(256) void vtrans_kernel(
    const ushort_t* __restrict__ qkv, ushort_t* __restrict__ Vt)
{
    __shared__ __align__(16) ushort_t tile[64][72];
    const int kvh = blockIdx.x & 7;
    const int s0 = (blockIdx.x >> 3) * 64;
    const int t = threadIdx.x;
    {
        const int sr = t >> 3;
        const int d8 = (t & 7) * 8;
        #pragma unroll
        for (int i = 0; i < 2; i++) {
            const int s = sr + i * 32;
            ushort_t tmp[8];
            *(uint4*)tmp = *(const uint4*)(qkv + (size_t)(s0 + s) * QKV_LD + 2560 + kvh * 64 + d8);
            #pragma unroll
            for (int j = 0; j < 8; j++) tile[d8 + j][s] = tmp[j];
        }
    }
    __syncthreads();
    {
        const int dr = t >> 3;
        const int s8 = (t & 7) * 8;
        #pragma unroll
        for (int i = 0; i < 2; i++) {
            const int d = dr + i * 32;
            *(uint4*)(Vt + ((size_t)kvh * 64 + d) * SEQ + s0 + s8) = *(const uint4*)&tile[d][s8];
        }
    }
}

// ---------------------------------------------------------------------------
// Flash attention, S^T orientation, work-uniform blocks.
// Block = 128 threads (2 waves), processes the causal-complementary PAIR of
// 64-query tiles (qt, 31-qt) sequentially -> (qt+1)+(32-qt)=33 key-tiles per
// block, zero variance. No block barriers; K/V read from L2; P^T via per-wave
// double-buffered LDS (write-visibility fence also covers WAR).
// Grid: 16 pairs * 32 heads = 512 blocks.
// ---------------------------------------------------------------------------
#define SPS 80   // sP row stride (ushorts)
__global__ __launch_bounds__(128) void attn_kernel(
    ushort_t* qkv, const ushort_t* __restrict__ Kr, const ushort_t* __restrict__ Vt)
{
    __shared__ __align__(16) ushort_t sP[2][2][16 * SPS];   // [wave][parity]

    const int t = threadIdx.x, wave = t >> 6, lane = t & 63;
    const int m16 = lane & 15, quad = lane >> 4;
    const int h = blockIdx.x & 31;
    const int pair = blockIdx.x >> 5;          // 0..15
    const int kvh = h >> 2;

    const ushort_t* Krh = Kr + (size_t)kvh * SEQ * 64;   // [s][d]
    const ushort_t* Vth = Vt + (size_t)kvh * 64 * SEQ;   // [d][s]

    #pragma unroll
    for (int ph = 0; ph < 2; ph++) {
        const int qt = ph ? (31 - pair) : pair;   // 64-query tile index
        const int qb = qt * 64;
        const int nkt = qt + 1;

        // Q fragments (B-operand layout): rows q0+m16, d = quad*8+j
        bf16x8 qf[2][2];
        #pragma unroll
        for (int qa = 0; qa < 2; qa++) {
            const int q0 = qb + (wave + qa * 2) * 16;
            const ushort_t* qp = qkv + (size_t)(q0 + m16) * QKV_LD + h * 64 + quad * 8;
            qf[qa][0] = *(const bf16x8*)qp;
            qf[qa][1] = *(const bf16x8*)(qp + 32);
        }

        f32x4 oacc[2][4] = {};                  // O^T: col=q(m16), row=d
        float m_run[2] = { -1e30f, -1e30f };
        float l_run[2] = { 0.f, 0.f };

        for (int kt = 0; kt < nkt; kt++) {
            const int kbase = kt * 64;
            const bool domask = (kt == nkt - 1);

            bf16x8 kf[4][2], vf[4][2];
            #pragma unroll
            for (int knt = 0; knt < 4; knt++) {
                const ushort_t* kp = Krh + (size_t)(kbase + knt * 16 + m16) * 64 + quad * 8;
                kf[knt][0] = *(const bf16x8*)kp;
                kf[knt][1] = *(const bf16x8*)(kp + 32);
            }
            #pragma unroll
            for (int nt = 0; nt < 4; nt++) {
                const ushort_t* vp = Vth + (size_t)(nt * 16 + m16) * SEQ + kbase + quad * 8;
                vf[nt][0] = *(const bf16x8*)vp;
                vf[nt][1] = *(const bf16x8*)(vp + 32);
            }

            #pragma unroll
            for (int qa = 0; qa < 2; qa++) {
                const int qi = qb + (wave + qa * 2) * 16 + m16;   // lane's query

                f32x4 sc[4] = {};
                #pragma unroll
                for (int knt = 0; knt < 4; knt++) {
                    sc[knt] = __builtin_amdgcn_mfma_f32_16x16x32_bf16(kf[knt][0], qf[qa][0], sc[knt], 0, 0, 0);
                    sc[knt] = __builtin_amdgcn_mfma_f32_16x16x32_bf16(kf[knt][1], qf[qa][1], sc[knt], 0, 0, 0);
                }

                float s[16];
                #pragma unroll
                for (int knt = 0; knt < 4; knt++)
                    #pragma unroll
                    for (int r = 0; r < 4; r++) {
                        float v = sc[knt][r] * 0.125f;
                        if (domask && (kbase + knt * 16 + quad * 4 + r > qi)) v = -1e30f;
                        s[knt * 4 + r] = v;
                    }

                float rmax = s[0];
                #pragma unroll
                for (int i = 1; i < 16; i++) rmax = fmaxf(rmax, s[i]);
                rmax = fmaxf(rmax, __shfl_xor(rmax, 16, 64));
                rmax = fmaxf(rmax, __shfl_xor(rmax, 32, 64));

                const float mnew = fmaxf(m_run[qa], rmax);
                const float alpha = __expf(m_run[qa] - mnew);
                m_run[qa] = mnew;

                float ps = 0.f;
                #pragma unroll
                for (int i = 0; i < 16; i++) { s[i] = __expf(s[i] - mnew); ps += s[i]; }
                ps += __shfl_xor(ps, 16, 64);
                ps += __shfl_xor(ps, 32, 64);
                l_run[qa] = l_run[qa] * alpha + ps;

                // ---- P^T -> per-wave dbuf LDS (col-major sP[q][key]) ----
                ushort_t* sPw = sP[wave][(kt * 2 + qa) & 1];
                #pragma unroll
                for (int knt = 0; knt < 4; knt++) {
                    unsigned int u0 = (unsigned int)f2bf(s[knt * 4 + 0]) | ((unsigned int)f2bf(s[knt * 4 + 1]) << 16);
                    unsigned int u1 = (unsigned int)f2bf(s[knt * 4 + 2]) | ((unsigned int)f2bf(s[knt * 4 + 3]) << 16);
                    uint2 pk; pk.x = u0; pk.y = u1;
                    *(uint2*)&sPw[m16 * SPS + knt * 16 + quad * 4] = pk;
                }
                lgkm_fence();   // writes visible; also drains prior buffer's reads
                bf16x8 pf0 = *(const bf16x8*)&sPw[m16 * SPS + quad * 8];
                bf16x8 pf1 = *(const bf16x8*)&sPw[m16 * SPS + 32 + quad * 8];

                // ---- O^T += V^T @ P^T ----
                #pragma unroll
                for (int nt = 0; nt < 4; nt++) {
                    #pragma unroll
                    for (int r = 0; r < 4; r++) oacc[qa][nt][r] *= alpha;
                    oacc[qa][nt] = __builtin_amdgcn_mfma_f32_16x16x32_bf16(vf[nt][0], pf0, oacc[qa][nt], 0, 0, 0);
                    oacc[qa][nt] = __builtin_amdgcn_mfma_f32_16x16x32_bf16(vf[nt][1], pf1, oacc[qa][nt], 0, 0, 0);
                }
            }
        }

        // ---- epilogue: O[q][h*64+d] = O^T/l ----
        #pragma unroll
        for (int qa = 0; qa < 2; qa++) {
            const int q = qb + (wave + qa * 2) * 16 + m16;
            const float rl = 1.f / l_run[qa];
            #pragma unroll
            for (int nt = 0; nt < 4; nt++) {
                ushort_t pk[4];
                #pragma unroll
                for (int r = 0; r < 4; r++) pk[r] = f2bf(oacc[qa][nt][r] * rl);
                *(uint2*)&qkv[(size_t)q * QKV_LD + h * 64 + nt * 16 + quad * 4] = *(uint2*)pk;
            }
        }
    }
}

// ---------------------------------------------------------------------------
extern "C" void kernel_launch(void* const* d_in, const int* in_sizes, int n_in,
                              void* d_out, int out_size, void* d_ws, size_t ws_size,
                              hipStream_t stream)
{
    const float* x  = (const float*)d_in[0];
    // d_in[1] = mask (int32) — causal, handled analytically
    const float* wq = (const float*)d_in[2];
    const float* wk = (const float*)d_in[3];
    const float* wv = (const float*)d_in[4];
    const float* wo = (const float*)d_in[5];

    ushort_t* WT  = (ushort_t*)d_ws;                    // [3072][2048] bf16
    ushort_t* xb  = WT + (size_t)3072 * 2048;           // [2048][2048] bf16
    ushort_t* woT = xb;                                 // alias: xb dead after QKV GEMM
    ushort_t* qkv = xb + (size_t)2048 * 2048;           // [2048][3072] bf16
    ushort_t* Kr  = qkv + (size_t)SEQ * QKV_LD;         // [8][2048][64]
    ushort_t* Vt  = Kr + (size_t)NKV * SEQ * HD;        // [8][64][2048]

    dim3 blk(256);

    convert_kernel<<<(DIM * SEQ) / 1024, blk, 0, stream>>>(x, xb);
    transpose_kernel<<<dim3(32, 32), blk, 0, stream>>>(wq, WT, 2048);
    transpose_kernel<<<dim3(8, 32),  blk, 0, stream>>>(wk, WT + (size_t)2048 * 2048, 512);
    transpose_kernel<<<dim3(8, 32),  blk, 0, stream>>>(wv, WT + (size_t)2560 * 2048, 512);

    // Fused QKV projection: [2048,2048] x [2048,3072] -> qkv
    gemm_kernel<0><<<dim3(QKV_LD / 128, SEQ / 128), blk, 0, stream>>>(xb, WT, qkv, DIM, DIM, QKV_LD);

    // wo transpose (reuses xb region — must follow the QKV GEMM)
    transpose_kernel<<<dim3(32, 32), blk, 0, stream>>>(wo, woT, 2048);

    // RoPE: SEQ*40 slices, one wave each
    rope_kernel<<<(SEQ * 40 * 64) / 256, blk, 0, stream>>>(qkv, Kr);
    vtrans_kernel<<<NKV * (SEQ / 64), blk, 0, stream>>>(qkv, Vt);

    attn_kernel<<<16 * NH, dim3(128), 0, stream>>>(qkv, Kr, Vt);

    // Output projection -> d_out fp32
    gemm_kernel<1><<<dim3(DIM / 128, SEQ / 128), blk, 0, stream>>>(qkv, woT, d_out, DIM, QKV_LD, DIM);
}